// Round 1
// baseline (128.054 us; speedup 1.0000x reference)
//
#include <hip/hip_runtime.h>
#include <hip/hip_bf16.h>

// CriticREM: out = relu(relu([state|action]W1^T+b1)W2^T+b2) @ Wc^T + bc
//   where Wc = sum_h alpha_h * Wh[h], bc = sum_h alpha_h * bh[h]
// B=65536, IN=128, HID=256, NUM_HEADS=200, OUT=1

#define B_TOTAL 65536
#define SDIM 96
#define ADIM 32
#define IN_F 128
#define HID 256
#define NHEADS 200
#define BM 64           // batch rows per block
#define XS_PITCH 136    // 128 + 8 bf16 pad (row stride 272B -> 2-way-only bank aliasing)
#define H1_PITCH 264    // 256 + 8 bf16 pad

typedef __bf16 bf16;
typedef __attribute__((ext_vector_type(8))) __bf16 bf16x8;
typedef __attribute__((ext_vector_type(4))) float f32x4;

// ---- prep: W1,W2 -> bf16 in ws; collapse heads: Wc[256], bc (fp32) ----
__global__ void prep_kernel(const float* __restrict__ W1, const float* __restrict__ W2,
                            const float* __restrict__ alphas, const float* __restrict__ Wh,
                            const float* __restrict__ bh,
                            bf16* __restrict__ W1bf, bf16* __restrict__ W2bf,
                            float* __restrict__ Wc) {
    int tid = blockIdx.x * blockDim.x + threadIdx.x;
    if (tid < IN_F * HID) W1bf[tid] = (bf16)W1[tid];
    if (tid < HID * HID)  W2bf[tid] = (bf16)W2[tid];
    if (tid < HID) {
        float acc = 0.f;
        for (int h = 0; h < NHEADS; ++h) acc += alphas[h] * Wh[h * HID + tid];
        Wc[tid] = acc;
    }
    if (tid == HID) {
        float acc = 0.f;
        for (int h = 0; h < NHEADS; ++h) acc += alphas[h] * bh[h];
        Wc[HID] = acc;   // bc
    }
}

// ---- main fused kernel: 256 threads (4 waves), 64 rows per block ----
__global__ __launch_bounds__(256, 2) void critic_kernel(
        const float* __restrict__ state, const float* __restrict__ action,
        const float* __restrict__ b1, const float* __restrict__ b2,
        const bf16* __restrict__ W1bf, const bf16* __restrict__ W2bf,
        const float* __restrict__ Wc, float* __restrict__ out) {

    __shared__ bf16 xs[BM * XS_PITCH];     // 17408 B
    __shared__ bf16 h1s[BM * H1_PITCH];    // 33792 B
    __shared__ float sWc[HID];             // 1024 B
    __shared__ float sPart[4][BM];         // 1024 B

    const int tid  = threadIdx.x;
    const int wave = tid >> 6;
    const int lane = tid & 63;
    const int q    = lane >> 4;     // 0..3 (k-quad / row-quad in MFMA layouts)
    const int ln   = lane & 15;     // 0..15
    const int colw = wave * 64;     // this wave's output-column slice
    const int row0 = blockIdx.x * BM;

    // stage Wc (head-collapsed weight vector)
    sWc[tid] = Wc[tid];

    // stage x = [state|action] as bf16 into LDS: 64 rows x 128 cols
    // 2048 float4 loads, 8 per thread, coalesced within rows
    #pragma unroll
    for (int i = 0; i < 8; ++i) {
        int idx = tid + i * 256;
        int r   = idx >> 5;          // 32 float4-chunks per row
        int c4  = idx & 31;
        float4 v;
        if (c4 < 24) v = ((const float4*)(state  + (size_t)(row0 + r) * SDIM))[c4];
        else         v = ((const float4*)(action + (size_t)(row0 + r) * ADIM))[c4 - 24];
        bf16* dst = &xs[r * XS_PITCH + c4 * 4];
        dst[0] = (bf16)v.x; dst[1] = (bf16)v.y; dst[2] = (bf16)v.z; dst[3] = (bf16)v.w;
    }
    __syncthreads();

    // ---- GEMM1: h1[64,256] = relu(x @ W1^T + b1); wave owns cols [colw, colw+64) ----
    f32x4 acc[4][4];
    #pragma unroll
    for (int mt = 0; mt < 4; ++mt)
        #pragma unroll
        for (int nt = 0; nt < 4; ++nt)
            acc[mt][nt] = (f32x4){0.f, 0.f, 0.f, 0.f};

    #pragma unroll
    for (int ks = 0; ks < 4; ++ks) {        // K = 128 = 4 x 32
        const int k0 = ks * 32 + q * 8;
        bf16x8 a[4], b[4];
        #pragma unroll
        for (int mt = 0; mt < 4; ++mt)
            a[mt] = *(const bf16x8*)&xs[(mt * 16 + ln) * XS_PITCH + k0];
        #pragma unroll
        for (int nt = 0; nt < 4; ++nt)
            b[nt] = *(const bf16x8*)&W1bf[(size_t)(colw + nt * 16 + ln) * IN_F + k0];
        #pragma unroll
        for (int mt = 0; mt < 4; ++mt)
            #pragma unroll
            for (int nt = 0; nt < 4; ++nt)
                acc[mt][nt] = __builtin_amdgcn_mfma_f32_16x16x32_bf16(a[mt], b[nt], acc[mt][nt], 0, 0, 0);
    }

    // epilogue 1: bias + relu, write bf16 h1 tile to LDS
    // C/D layout: col = ln, row = q*4 + reg  [m89/m91]
    #pragma unroll
    for (int nt = 0; nt < 4; ++nt) {
        const int n    = colw + nt * 16 + ln;
        const float bias = b1[n];
        #pragma unroll
        for (int mt = 0; mt < 4; ++mt)
            #pragma unroll
            for (int r = 0; r < 4; ++r) {
                float v = acc[mt][nt][r] + bias;
                v = v > 0.f ? v : 0.f;
                h1s[(mt * 16 + q * 4 + r) * H1_PITCH + n] = (bf16)v;
            }
    }
    __syncthreads();

    // ---- GEMM2: h2[64,256] = relu(h1 @ W2^T + b2) ----
    #pragma unroll
    for (int mt = 0; mt < 4; ++mt)
        #pragma unroll
        for (int nt = 0; nt < 4; ++nt)
            acc[mt][nt] = (f32x4){0.f, 0.f, 0.f, 0.f};

    #pragma unroll
    for (int ks = 0; ks < 8; ++ks) {        // K = 256 = 8 x 32
        const int k0 = ks * 32 + q * 8;
        bf16x8 a[4], b[4];
        #pragma unroll
        for (int mt = 0; mt < 4; ++mt)
            a[mt] = *(const bf16x8*)&h1s[(mt * 16 + ln) * H1_PITCH + k0];
        #pragma unroll
        for (int nt = 0; nt < 4; ++nt)
            b[nt] = *(const bf16x8*)&W2bf[(size_t)(colw + nt * 16 + ln) * HID + k0];
        #pragma unroll
        for (int mt = 0; mt < 4; ++mt)
            #pragma unroll
            for (int nt = 0; nt < 4; ++nt)
                acc[mt][nt] = __builtin_amdgcn_mfma_f32_16x16x32_bf16(a[mt], b[nt], acc[mt][nt], 0, 0, 0);
    }

    // epilogue 2: bias + relu + dot with Wc, all in-register
    float partial[4][4];
    #pragma unroll
    for (int mt = 0; mt < 4; ++mt)
        #pragma unroll
        for (int r = 0; r < 4; ++r)
            partial[mt][r] = 0.f;

    #pragma unroll
    for (int nt = 0; nt < 4; ++nt) {
        const int n     = colw + nt * 16 + ln;
        const float bias = b2[n];
        const float wc   = sWc[n];
        #pragma unroll
        for (int mt = 0; mt < 4; ++mt)
            #pragma unroll
            for (int r = 0; r < 4; ++r) {
                float v = acc[mt][nt][r] + bias;
                v = v > 0.f ? v : 0.f;
                partial[mt][r] += v * wc;
            }
    }

    // reduce over the 16 lanes (ln dim) that share rows
    #pragma unroll
    for (int off = 1; off < 16; off <<= 1)
        #pragma unroll
        for (int mt = 0; mt < 4; ++mt)
            #pragma unroll
            for (int r = 0; r < 4; ++r)
                partial[mt][r] += __shfl_xor(partial[mt][r], off, 64);

    if (ln == 0) {
        #pragma unroll
        for (int mt = 0; mt < 4; ++mt)
            #pragma unroll
            for (int r = 0; r < 4; ++r)
                sPart[wave][mt * 16 + q * 4 + r] = partial[mt][r];
    }
    __syncthreads();

    // combine the 4 wave column-slices + bc, write out
    if (tid < BM) {
        float v = sPart[0][tid] + sPart[1][tid] + sPart[2][tid] + sPart[3][tid] + Wc[HID];
        out[row0 + tid] = v;
    }
}

extern "C" void kernel_launch(void* const* d_in, const int* in_sizes, int n_in,
                              void* d_out, int out_size, void* d_ws, size_t ws_size,
                              hipStream_t stream) {
    const float* state  = (const float*)d_in[0];
    const float* action = (const float*)d_in[1];
    const float* alphas = (const float*)d_in[2];
    const float* W1     = (const float*)d_in[3];
    const float* b1     = (const float*)d_in[4];
    const float* W2     = (const float*)d_in[5];
    const float* b2     = (const float*)d_in[6];
    const float* Wh     = (const float*)d_in[7];
    const float* bh     = (const float*)d_in[8];
    float* out = (float*)d_out;

    bf16*  W1bf = (bf16*)d_ws;                                  // 65536 B
    bf16*  W2bf = (bf16*)((char*)d_ws + 65536);                 // 131072 B
    float* Wc   = (float*)((char*)d_ws + 65536 + 131072);       // 257 * 4 B

    prep_kernel<<<256, 256, 0, stream>>>(W1, W2, alphas, Wh, bh, W1bf, W2bf, Wc);
    critic_kernel<<<B_TOTAL / BM, 256, 0, stream>>>(state, action, b1, b2, W1bf, W2bf, Wc, out);
}